// Round 8
// baseline (331.525 us; speedup 1.0000x reference)
//
#include <hip/hip_runtime.h>
#include <math.h>

constexpr int BB = 64, NN = 512, DD = 128, UU = 64;
constexpr float KCOUL = 14.399645351950548f;
constexpr float NOISEF = 1e-8f;
#define M_PIF 3.14159265358979323846f

typedef __attribute__((ext_vector_type(8))) short bfrag;   // 8 bf16 (4 VGPRs)
typedef __attribute__((ext_vector_type(4))) float ffrag;   // 4 fp32 acc

__device__ __forceinline__ unsigned short f2bf(float f) {   // RNE float->bf16
  unsigned int u = __float_as_uint(f);
  u += 0x7fffu + ((u >> 16) & 1u);
  return (unsigned short)(u >> 16);
}
__device__ __forceinline__ float bf2f(unsigned short h) {
  return __uint_as_float((unsigned int)h << 16);
}
// Two-regime erf:
//  x < 0.5 : odd Taylor, RELATIVE err <= ~8e-7 (safe inside erf(x)/x forms)
//  x >= 0.5: A&S 7.1.26, abs err < 1.5e-7 (erf >= 0.52 there, no cancellation)
__device__ __forceinline__ float fast_erf(float x) {
  float t2 = x * x;
  float small_v = 1.1283791671f * x *
      fmaf(t2, fmaf(t2, fmaf(t2, fmaf(t2, 4.6296296e-3f, -2.3809524e-2f),
                             0.1f), -0.33333333f), 1.0f);
  float t = __builtin_amdgcn_rcpf(fmaf(0.3275911f, x, 1.0f));
  float p = fmaf(fmaf(fmaf(fmaf(1.061405429f, t, -1.453152027f),
                           t, 1.421413741f), t, -0.284496736f), t, 0.254829592f);
  float big_v = fmaf(-p * t, __expf(-t2), 1.0f);
  return x < 0.5f ? small_v : big_v;
}

// ---------------- chi MLP: one wave (64 lanes) per row, 4 rows/block ----------
__global__ __launch_bounds__(256) void chi_kernel(
    const float* __restrict__ feats, const float* __restrict__ W1,
    const float* __restrict__ b1, const float* __restrict__ W2,
    const float* __restrict__ b2, const float* __restrict__ W3,
    const float* __restrict__ b3, float* __restrict__ chi)
{
  int wave = threadIdx.x >> 6, lane = threadIdx.x & 63;
  int row = (blockIdx.x << 2) + wave;
  __shared__ float sf[4][DD];
  __shared__ float sh[4][UU];
  const float* f = feats + (size_t)row * DD;
  sf[wave][lane] = f[lane];
  sf[wave][lane + 64] = f[lane + 64];
  __syncthreads();
  float a = b1[lane];
  #pragma unroll 8
  for (int d = 0; d < DD; ++d) a = fmaf(sf[wave][d], W1[d * UU + lane], a);
  float h1 = a - tanhf(a);            // tanhshrink
  sh[wave][lane] = h1;
  __syncthreads();
  float a2 = b2[lane];
  #pragma unroll 8
  for (int i = 0; i < UU; ++i) a2 = fmaf(sh[wave][i], W2[i * UU + lane], a2);
  float h2 = a2 - tanhf(a2);
  float prod = h2 * W3[lane];
  #pragma unroll
  for (int off = 32; off; off >>= 1) prod += __shfl_down(prod, off, 64);
  if (lane == 0) {
    float z = prod + b3[0];
    chi[row] = z - tanhf(z);
  }
}

// ------ build A (fp32 to d_out) + bf16 copy in MFMA fragment-major layout ----
// swizzle: (i,j) -> (i>>4)*8192 + (j>>5)*512 + ((j>>3)&3)*128 + (i&15)*8 + (j&7)
__global__ __launch_bounds__(256) void build_A_kernel(
    const float* __restrict__ pos, const int* __restrict__ ntype,
    const float* __restrict__ hardness, const float* __restrict__ sigma,
    float* __restrict__ Aout, unsigned short* __restrict__ Abf)
{
  int b = blockIdx.y;
  int r0 = blockIdx.x * 16;
  __shared__ float px[NN], py[NN], pz[NN], s2[NN], hd[NN];
  for (int n = threadIdx.x; n < NN; n += 256) {
    const float* p = pos + ((size_t)b * NN + n) * 3;
    px[n] = p[0]; py[n] = p[1]; pz[n] = p[2];
    int ty = ntype[b * NN + n];
    float s = sigma[ty];
    s2[n] = s * s;
    hd[n] = hardness[ty];
  }
  __syncthreads();
  int c0 = (threadIdx.x & 127) << 2;
  int rsub = threadIdx.x >> 7;
  float* outB = Aout + (size_t)b * NN * NN;
  unsigned short* bfB = Abf ? Abf + (size_t)b * NN * NN : nullptr;
  for (int k = 0; k < 8; ++k) {
    int i = r0 + (k << 1) + rsub;
    float pxi = px[i], pyi = py[i], pzi = pz[i], s2i = s2[i];
    float4 v;
    float* vp = &v.x;
    #pragma unroll
    for (int c = 0; c < 4; ++c) {
      int j = c0 + c;
      float dx = pxi - px[j], dy = pyi - py[j], dz = pzi - pz[j];
      float d = sqrtf(fmaf(dx, dx, fmaf(dy, dy, dz * dz))) + NOISEF;
      float arg = d * __builtin_amdgcn_rsqf(2.0f * (s2i + s2[j]));
      float val = KCOUL * fast_erf(arg) * __builtin_amdgcn_rcpf(d);
      if (j == i) val += hd[i] + KCOUL * __builtin_amdgcn_rsqf(2.0f * M_PIF * s2i);
      vp[c] = val;
    }
    *reinterpret_cast<float4*>(outB + (size_t)i * NN + c0) = v;
    if (bfB) {
      ushort4 wv;
      wv.x = f2bf(v.x); wv.y = f2bf(v.y); wv.z = f2bf(v.z); wv.w = f2bf(v.w);
      size_t off = ((size_t)(i >> 4) << 13) + ((size_t)(c0 >> 5) << 9)
                 + (((c0 >> 3) & 3) << 7) + ((i & 15) << 3) + (c0 & 7);
      *reinterpret_cast<ushort4*>(bfB + off) = wv;
    }
  }
}

// ---------------- shared reduction helpers -----------------------------------
__device__ __forceinline__ float4 blockReduce4(float4 v, float4* wred, int t) {
  #pragma unroll
  for (int off = 32; off; off >>= 1) {
    v.x += __shfl_down(v.x, off, 64);
    v.y += __shfl_down(v.y, off, 64);
    v.z += __shfl_down(v.z, off, 64);
    v.w += __shfl_down(v.w, off, 64);
  }
  __syncthreads();
  if ((t & 63) == 0) wred[t >> 6] = v;
  __syncthreads();
  float4 r = wred[0];
  #pragma unroll
  for (int k = 1; k < 16; ++k) {
    float4 u = wred[k];
    r.x += u.x; r.y += u.y; r.z += u.z; r.w += u.w;
  }
  return r;
}

// ------- Chronopoulos-Gear CG, MFMA hi/lo matvec, 1 block per batch ----------
// per iter: w = A r (bf16 hi/lo);  ONE reduce (mu=r.r, nu=r.w);  then
// beta = mu/mu_old; alpha = mu/(nu - beta*mu/alpha_old);
// p = r + beta p; q = w + beta q; x += alpha p; r -= alpha q  (one phase).
__global__ __launch_bounds__(1024) void cg_kernel_bf(
    const unsigned short* __restrict__ Abf, const float* __restrict__ tq,
    float* __restrict__ qout /* in: chi, out: charges */)
{
  int b = blockIdx.x;
  const unsigned short* A = Abf + (size_t)b * NN * NN;
  int t = threadIdx.x;
  int lane = t & 63, w = t >> 6;          // 16 waves
  constexpr int PAD = NN + 32;            // 544 shorts -> +16 banks per buffer
  __shared__ float2 p01[NN], q01[NN], r01[NN], x01[NN], w01[NN];
  __shared__ __align__(16) unsigned short rsplit[4 * PAD]; // hi0,hi1,lo0,lo1
  __shared__ float4 wred[16];

  float2 z2 = make_float2(0.f, 0.f);
  float2 rsq = z2;
  if (t < NN) {
    float c = qout[b * NN + t];            // chi
    float2 rv = make_float2(-c, 1.0f);     // rhs0 = -chi ; rhs1 = ones
    r01[t] = rv; x01[t] = z2; p01[t] = z2; q01[t] = z2;
    unsigned short h0 = f2bf(rv.x), h1 = f2bf(rv.y);
    rsplit[t] = h0;            rsplit[PAD + t] = h1;
    rsplit[2 * PAD + t] = f2bf(rv.x - bf2f(h0));
    rsplit[3 * PAD + t] = f2bf(rv.y - bf2f(h1));
    rsq = make_float2(rv.x * rv.x, rv.y * rv.y);
  }
  float4 rr0 = blockReduce4(make_float4(rsq.x, rsq.y, 0.f, 0.f), wred, t);
  float tol0 = fmaxf(1e-6f * rr0.x, 1e-12f);   // rel residual 1e-3
  float tol1 = fmaxf(1e-6f * rr0.y, 1e-12f);
  bool act0 = rr0.x > tol0, act1 = rr0.y > tol1;

  const int m  = lane & 15;               // A row within tile / B col n
  const int qd = lane >> 4;               // quad: k-subrange qd*8..+7
  const unsigned short* aw0 = A + ((size_t)(2 * w) << 13) + lane * 8;
  const unsigned short* aw1 = aw0 + 8192;
  const unsigned short* bhi = rsplit + (m & 1) * PAD;          // banks 0-15/16-31
  const unsigned short* blo = rsplit + 2 * PAD + (m & 1) * PAD;

  float muold0 = 1.f, muold1 = 1.f, alold0 = 1.f, alold1 = 1.f;
  for (int k = 0; k < 48 && (act0 || act1); ++k) {
    // ---- matvec: w = A*(r_hi) + A*(r_lo), two 16-row tiles per wave ----
    ffrag acc0 = {0.f, 0.f, 0.f, 0.f};
    ffrag acc1 = {0.f, 0.f, 0.f, 0.f};
    #pragma unroll 4
    for (int c = 0; c < 16; ++c) {
      int bo = c * 32 + qd * 8;
      bfrag bh = *reinterpret_cast<const bfrag*>(bhi + bo);
      bfrag bl = *reinterpret_cast<const bfrag*>(blo + bo);
      bfrag a0 = *reinterpret_cast<const bfrag*>(aw0 + c * 512);
      bfrag a1 = *reinterpret_cast<const bfrag*>(aw1 + c * 512);
      acc0 = __builtin_amdgcn_mfma_f32_16x16x32_bf16(a0, bh, acc0, 0, 0, 0);
      acc0 = __builtin_amdgcn_mfma_f32_16x16x32_bf16(a0, bl, acc0, 0, 0, 0);
      acc1 = __builtin_amdgcn_mfma_f32_16x16x32_bf16(a1, bh, acc1, 0, 0, 0);
      acc1 = __builtin_amdgcn_mfma_f32_16x16x32_bf16(a1, bl, acc1, 0, 0, 0);
    }
    if (m < 2) {                           // D: col=lane&15 (rhs), row=qd*4+reg
      int rbase = qd * 4;
      #pragma unroll
      for (int r = 0; r < 4; ++r) {
        reinterpret_cast<float*>(&w01[w * 32 + rbase + r])[m]      = acc0[r];
        reinterpret_cast<float*>(&w01[w * 32 + 16 + rbase + r])[m] = acc1[r];
      }
    }
    __syncthreads();

    // ---- ONE joint reduction: (r.r, r.w) for both RHS ----
    float4 dp = make_float4(0.f, 0.f, 0.f, 0.f);
    if (t < NN) {
      float2 rv = r01[t], wv = w01[t];
      dp = make_float4(rv.x * rv.x, rv.x * wv.x, rv.y * rv.y, rv.y * wv.y);
    }
    float4 s = blockReduce4(dp, wred, t);
    if (act0 && s.x <= tol0) act0 = false;
    if (act1 && s.z <= tol1) act1 = false;
    if (!act0 && !act1) break;
    float be0 = 0.f, al0 = 0.f, be1 = 0.f, al1 = 0.f;
    if (act0) {
      be0 = k ? s.x / muold0 : 0.f;
      al0 = s.x / (s.y - be0 * s.x / alold0);
      muold0 = s.x; alold0 = al0;
    }
    if (act1) {
      be1 = k ? s.z / muold1 : 0.f;
      al1 = s.z / (s.w - be1 * s.z / alold1);
      muold1 = s.z; alold1 = al1;
    }

    // ---- fused vector phase: p,q,x,r recurrences + hi/lo split of new r ----
    if (t < NN) {
      float2 rv = r01[t], wv = w01[t], pv = p01[t], qv = q01[t], xv = x01[t];
      if (act0) {
        pv.x = fmaf(be0, pv.x, rv.x);
        qv.x = fmaf(be0, qv.x, wv.x);
        xv.x = fmaf(al0, pv.x, xv.x);
        rv.x = fmaf(-al0, qv.x, rv.x);
      }
      if (act1) {
        pv.y = fmaf(be1, pv.y, rv.y);
        qv.y = fmaf(be1, qv.y, wv.y);
        xv.y = fmaf(al1, pv.y, xv.y);
        rv.y = fmaf(-al1, qv.y, rv.y);
      }
      p01[t] = pv; q01[t] = qv; x01[t] = xv; r01[t] = rv;
      unsigned short h0 = f2bf(rv.x), h1 = f2bf(rv.y);
      rsplit[t] = h0;            rsplit[PAD + t] = h1;
      rsplit[2 * PAD + t] = f2bf(rv.x - bf2f(h0));
      rsplit[3 * PAD + t] = f2bf(rv.y - bf2f(h1));
    }
    __syncthreads();
  }

  // ---- epilogue: lambda = (1'y - Q)/(1'z); charges = y - lambda*z ----
  float2 sv = z2;
  if (t < NN) sv = x01[t];
  float4 s = blockReduce4(make_float4(sv.x, sv.y, 0.f, 0.f), wred, t);
  float lam = (s.x - tq[b]) / s.y;
  if (t < NN) qout[b * NN + t] = x01[t].x - lam * x01[t].y;
}

// ---------------- fp32 fallback (round-3 structure) --------------------------
__device__ __forceinline__ float2 blockReduce2(float2 v, float2* wred, int t) {
  #pragma unroll
  for (int off = 32; off; off >>= 1) {
    v.x += __shfl_down(v.x, off, 64);
    v.y += __shfl_down(v.y, off, 64);
  }
  __syncthreads();
  if ((t & 63) == 0) wred[t >> 6] = v;
  __syncthreads();
  float2 r = wred[0];
  #pragma unroll
  for (int k = 1; k < 16; ++k) { r.x += wred[k].x; r.y += wred[k].y; }
  return r;
}

__global__ __launch_bounds__(1024) void cg_kernel_f32(
    const float* __restrict__ Aall, const float* __restrict__ tq,
    float* __restrict__ qout)
{
  int b = blockIdx.x;
  const float* A = Aall + (size_t)b * NN * NN;
  int t = threadIdx.x;
  __shared__ float2 p01[NN], q01[NN], r01[NN], x01[NN];
  __shared__ float4 sacc0[8][128];
  __shared__ float4 sacc1[8][128];
  __shared__ float2 wred[16];

  float2 z2 = make_float2(0.f, 0.f);
  float2 rsq = z2;
  if (t < NN) {
    float b0 = -qout[b * NN + t];
    x01[t] = z2;
    r01[t] = make_float2(b0, 1.0f);
    p01[t] = make_float2(b0, 1.0f);
    rsq = make_float2(b0 * b0, 1.0f);
  }
  float2 rr = blockReduce2(rsq, wred, t);
  float tol0 = fmaxf(1e-6f * rr.x, 1e-12f);
  float tol1 = fmaxf(1e-6f * rr.y, 1e-12f);
  const int c4 = (t & 127) << 2;
  const int jr = t >> 7;
  for (int it = 0; it < 48; ++it) {
    bool act0 = rr.x > tol0, act1 = rr.y > tol1;
    if (!act0 && !act1) break;
    {
      const float* ap = A + (size_t)(jr * 64) * NN + c4;
      float4 a0 = make_float4(0.f, 0.f, 0.f, 0.f);
      float4 a1 = a0;
      #pragma unroll 8
      for (int mI = 0; mI < 64; ++mI) {
        float4 av = *reinterpret_cast<const float4*>(ap);
        ap += NN;
        float2 pj = p01[jr * 64 + mI];
        a0.x = fmaf(av.x, pj.x, a0.x); a0.y = fmaf(av.y, pj.x, a0.y);
        a0.z = fmaf(av.z, pj.x, a0.z); a0.w = fmaf(av.w, pj.x, a0.w);
        a1.x = fmaf(av.x, pj.y, a1.x); a1.y = fmaf(av.y, pj.y, a1.y);
        a1.z = fmaf(av.z, pj.y, a1.z); a1.w = fmaf(av.w, pj.y, a1.w);
      }
      sacc0[jr][t & 127] = a0;
      sacc1[jr][t & 127] = a1;
    }
    __syncthreads();
    float2 dv = z2;
    if (t < NN) {
      const float* f0 = reinterpret_cast<const float*>(sacc0);
      const float* f1 = reinterpret_cast<const float*>(sacc1);
      float s0 = 0.f, s1 = 0.f;
      #pragma unroll
      for (int g = 0; g < 8; ++g) { s0 += f0[g * 512 + t]; s1 += f1[g * 512 + t]; }
      q01[t] = make_float2(s0, s1);
      float2 pv = p01[t];
      dv.x = s0 * pv.x; dv.y = s1 * pv.y;
    }
    float2 pq = blockReduce2(dv, wred, t);
    float al0 = act0 ? rr.x / pq.x : 0.f;
    float al1 = act1 ? rr.y / pq.y : 0.f;
    float2 rn = z2;
    if (t < NN) {
      float2 xv = x01[t], rv = r01[t], pv = p01[t], qv = q01[t];
      xv.x = fmaf(al0, pv.x, xv.x);  xv.y = fmaf(al1, pv.y, xv.y);
      rv.x = fmaf(-al0, qv.x, rv.x); rv.y = fmaf(-al1, qv.y, rv.y);
      x01[t] = xv; r01[t] = rv;
      rn.x = rv.x * rv.x; rn.y = rv.y * rv.y;
    }
    float2 rrn = blockReduce2(rn, wred, t);
    float be0 = act0 ? rrn.x / rr.x : 0.f;
    float be1 = act1 ? rrn.y / rr.y : 0.f;
    if (t < NN) {
      float2 rv = r01[t], pv = p01[t];
      pv.x = fmaf(be0, pv.x, rv.x);
      pv.y = fmaf(be1, pv.y, rv.y);
      p01[t] = pv;
    }
    rr = rrn;
    __syncthreads();
  }
  float2 sv = z2;
  if (t < NN) sv = x01[t];
  float2 s = blockReduce2(sv, wred, t);
  float lam = (s.x - tq[b]) / s.y;
  if (t < NN) qout[b * NN + t] = x01[t].x - lam * x01[t].y;
}

extern "C" void kernel_launch(void* const* d_in, const int* in_sizes, int n_in,
                              void* d_out, int out_size, void* d_ws, size_t ws_size,
                              hipStream_t stream) {
  const float* pos      = (const float*)d_in[0];
  const float* feats    = (const float*)d_in[1];
  const int*   ntype    = (const int*)  d_in[2];
  const float* tq       = (const float*)d_in[3];
  const float* hardness = (const float*)d_in[4];
  const float* sigma    = (const float*)d_in[5];
  const float* W1 = (const float*)d_in[6];
  const float* b1 = (const float*)d_in[7];
  const float* W2 = (const float*)d_in[8];
  const float* b2 = (const float*)d_in[9];
  const float* W3 = (const float*)d_in[10];
  const float* b3 = (const float*)d_in[11];

  float* out  = (float*)d_out;
  float* chi  = out;             // charges region doubles as chi scratch
  float* Aout = out + BB * NN;   // output 1: A, batch-major

  const size_t bf_bytes = (size_t)BB * NN * NN * sizeof(unsigned short);
  const bool use_bf = ws_size >= bf_bytes;
  unsigned short* Abf = use_bf ? (unsigned short*)d_ws : nullptr;

  chi_kernel<<<dim3(BB * NN / 4), dim3(256), 0, stream>>>(feats, W1, b1, W2, b2, W3, b3, chi);
  build_A_kernel<<<dim3(NN / 16, BB), dim3(256), 0, stream>>>(pos, ntype, hardness, sigma, Aout, Abf);
  if (use_bf)
    cg_kernel_bf<<<dim3(BB), dim3(1024), 0, stream>>>(Abf, tq, chi);
  else
    cg_kernel_f32<<<dim3(BB), dim3(1024), 0, stream>>>(Aout, tq, chi);
}

// Round 9
// 254.994 us; speedup vs baseline: 1.3001x; 1.3001x over previous
//
#include <hip/hip_runtime.h>
#include <math.h>

constexpr int BB = 64, NN = 512, DD = 128, UU = 64;
constexpr float KCOUL = 14.399645351950548f;
constexpr float NOISEF = 1e-8f;
#define M_PIF 3.14159265358979323846f

typedef __attribute__((ext_vector_type(8))) short bfrag;   // 8 bf16 (4 VGPRs)
typedef __attribute__((ext_vector_type(4))) float ffrag;   // 4 fp32 acc

__device__ __forceinline__ unsigned short f2bf(float f) {   // RNE float->bf16
  unsigned int u = __float_as_uint(f);
  u += 0x7fffu + ((u >> 16) & 1u);
  return (unsigned short)(u >> 16);
}
__device__ __forceinline__ float bf2f(unsigned short h) {
  return __uint_as_float((unsigned int)h << 16);
}
// Two-regime erf (rel-accurate near 0 — required inside erf(x)/x):
__device__ __forceinline__ float fast_erf(float x) {
  float t2 = x * x;
  float small_v = 1.1283791671f * x *
      fmaf(t2, fmaf(t2, fmaf(t2, fmaf(t2, 4.6296296e-3f, -2.3809524e-2f),
                             0.1f), -0.33333333f), 1.0f);
  float t = __builtin_amdgcn_rcpf(fmaf(0.3275911f, x, 1.0f));
  float p = fmaf(fmaf(fmaf(fmaf(1.061405429f, t, -1.453152027f),
                           t, 1.421413741f), t, -0.284496736f), t, 0.254829592f);
  float big_v = fmaf(-p * t, __expf(-t2), 1.0f);
  return x < 0.5f ? small_v : big_v;
}
__device__ __forceinline__ float fast_tanh(float x) {      // rel err ~1e-6
  float ax = fabsf(x);
  float e = __expf(2.0f * ax);
  float t = 1.0f - 2.0f * __builtin_amdgcn_rcpf(e + 1.0f);
  return __builtin_copysignf(t, x);
}

// ------- chi MLP: 4 rows per wave, scalar(SGPR) feats, W1/W2 amortized -------
__global__ __launch_bounds__(256) void chi_kernel(
    const float* __restrict__ feats, const float* __restrict__ W1,
    const float* __restrict__ b1, const float* __restrict__ W2,
    const float* __restrict__ b2, const float* __restrict__ W3,
    const float* __restrict__ b3, float* __restrict__ chi)
{
  int wave = threadIdx.x >> 6, lane = threadIdx.x & 63;
  int row0 = __builtin_amdgcn_readfirstlane((blockIdx.x * 4 + wave) * 4);
  const float* f = feats + (size_t)row0 * DD;   // SGPR base -> s_load
  __shared__ float sh[4][4][UU];

  float a0 = b1[lane], a1 = a0, a2 = a0, a3 = a0;
  #pragma unroll 8
  for (int d = 0; d < DD; ++d) {
    float wv = W1[d * UU + lane];               // coalesced, L1-resident
    a0 = fmaf(f[d],          wv, a0);
    a1 = fmaf(f[DD + d],     wv, a1);
    a2 = fmaf(f[2 * DD + d], wv, a2);
    a3 = fmaf(f[3 * DD + d], wv, a3);
  }
  sh[wave][0][lane] = a0 - fast_tanh(a0);
  sh[wave][1][lane] = a1 - fast_tanh(a1);
  sh[wave][2][lane] = a2 - fast_tanh(a2);
  sh[wave][3][lane] = a3 - fast_tanh(a3);
  __builtin_amdgcn_s_waitcnt(0);                // lgkm drain before ds_read
  float c0 = b2[lane], c1 = c0, c2 = c0, c3 = c0;
  #pragma unroll 8
  for (int u = 0; u < UU; ++u) {
    float wv = W2[u * UU + lane];
    c0 = fmaf(sh[wave][0][u], wv, c0);          // LDS same-addr broadcast
    c1 = fmaf(sh[wave][1][u], wv, c1);
    c2 = fmaf(sh[wave][2][u], wv, c2);
    c3 = fmaf(sh[wave][3][u], wv, c3);
  }
  float w3 = W3[lane];
  float p0 = (c0 - fast_tanh(c0)) * w3;
  float p1 = (c1 - fast_tanh(c1)) * w3;
  float p2 = (c2 - fast_tanh(c2)) * w3;
  float p3 = (c3 - fast_tanh(c3)) * w3;
  #pragma unroll
  for (int off = 32; off; off >>= 1) {
    p0 += __shfl_down(p0, off, 64);
    p1 += __shfl_down(p1, off, 64);
    p2 += __shfl_down(p2, off, 64);
    p3 += __shfl_down(p3, off, 64);
  }
  if (lane == 0) {
    float bb = b3[0];
    float z0 = p0 + bb, z1 = p1 + bb, z2v = p2 + bb, z3 = p3 + bb;
    chi[row0]     = z0 - fast_tanh(z0);
    chi[row0 + 1] = z1 - fast_tanh(z1);
    chi[row0 + 2] = z2v - fast_tanh(z2v);
    chi[row0 + 3] = z3 - fast_tanh(z3);
  }
}

// ------ build A (fp32 coalesced to d_out) + bf16 frag-tile staged in LDS -----
// frag layout: (i,j) -> (i>>4)*8192 + (j>>5)*512 + ((j>>3)&3)*128 + (i&15)*8 + (j&7)
__global__ __launch_bounds__(256) void build_A_kernel(
    const float* __restrict__ pos, const int* __restrict__ ntype,
    const float* __restrict__ hardness, const float* __restrict__ sigma,
    float* __restrict__ Aout, unsigned short* __restrict__ Abf)
{
  int b = blockIdx.y;
  int r0 = blockIdx.x * 16;                  // exactly one 16-row frag tile
  __shared__ float px[NN], py[NN], pz[NN], s2[NN], hd[NN];
  __shared__ unsigned short tile[16 * NN];   // 16 KB frag-major bf16
  for (int n = threadIdx.x; n < NN; n += 256) {
    const float* p = pos + ((size_t)b * NN + n) * 3;
    px[n] = p[0]; py[n] = p[1]; pz[n] = p[2];
    int ty = ntype[b * NN + n];
    float s = sigma[ty];
    s2[n] = s * s;
    hd[n] = hardness[ty];
  }
  __syncthreads();
  int c0 = (threadIdx.x & 127) << 2;
  int rsub = threadIdx.x >> 7;
  float* outB = Aout + (size_t)b * NN * NN;
  for (int k = 0; k < 8; ++k) {
    int i = r0 + (k << 1) + rsub;
    float pxi = px[i], pyi = py[i], pzi = pz[i], s2i = s2[i];
    float4 v;
    float* vp = &v.x;
    #pragma unroll
    for (int c = 0; c < 4; ++c) {
      int j = c0 + c;
      float dx = pxi - px[j], dy = pyi - py[j], dz = pzi - pz[j];
      float d = sqrtf(fmaf(dx, dx, fmaf(dy, dy, dz * dz))) + NOISEF;
      float arg = d * __builtin_amdgcn_rsqf(2.0f * (s2i + s2[j]));
      float val = KCOUL * fast_erf(arg) * __builtin_amdgcn_rcpf(d);
      if (j == i) val += hd[i] + KCOUL * __builtin_amdgcn_rsqf(2.0f * M_PIF * s2i);
      vp[c] = val;
    }
    *reinterpret_cast<float4*>(outB + (size_t)i * NN + c0) = v;
    if (Abf) {
      ushort4 wv;
      wv.x = f2bf(v.x); wv.y = f2bf(v.y); wv.z = f2bf(v.z); wv.w = f2bf(v.w);
      int loc = ((c0 >> 5) << 9) + (((c0 >> 3) & 3) << 7) + ((i & 15) << 3) + (c0 & 7);
      *reinterpret_cast<ushort4*>(tile + loc) = wv;
    }
  }
  if (Abf) {
    __syncthreads();
    const uint4* src = reinterpret_cast<const uint4*>(tile);
    uint4* dst = reinterpret_cast<uint4*>(Abf + (size_t)b * NN * NN +
                                          ((size_t)(r0 >> 4) << 13));
    #pragma unroll
    for (int k = 0; k < 4; ++k)                 // 1024 uint4 = 16 KB coalesced
      dst[threadIdx.x + k * 256] = src[threadIdx.x + k * 256];
  }
}

// ---------------- shared reduction helper ------------------------------------
__device__ __forceinline__ float4 blockReduce4(float4 v, float4* wred, int t) {
  #pragma unroll
  for (int off = 32; off; off >>= 1) {
    v.x += __shfl_down(v.x, off, 64);
    v.y += __shfl_down(v.y, off, 64);
    v.z += __shfl_down(v.z, off, 64);
    v.w += __shfl_down(v.w, off, 64);
  }
  __syncthreads();
  if ((t & 63) == 0) wred[t >> 6] = v;
  __syncthreads();
  float4 r = wred[0];
  #pragma unroll
  for (int k = 1; k < 16; ++k) {
    float4 u = wred[k];
    r.x += u.x; r.y += u.y; r.z += u.z; r.w += u.w;
  }
  return r;
}

// ------- Chronopoulos-Gear CG, MFMA hi/lo matvec, 1 block per batch ----------
// tol: rel residual 1e-2 (just above the measured ~5e-3 hi/lo stall floor);
// cap 24 — beyond the stall, extra iterations don't improve the true residual.
__global__ __launch_bounds__(1024) void cg_kernel_bf(
    const unsigned short* __restrict__ Abf, const float* __restrict__ tq,
    float* __restrict__ qout /* in: chi, out: charges */)
{
  int b = blockIdx.x;
  const unsigned short* A = Abf + (size_t)b * NN * NN;
  int t = threadIdx.x;
  int lane = t & 63, w = t >> 6;          // 16 waves
  constexpr int PAD = NN + 32;
  __shared__ float2 p01[NN], q01[NN], r01[NN], x01[NN], w01[NN];
  __shared__ __align__(16) unsigned short rsplit[4 * PAD]; // hi0,hi1,lo0,lo1
  __shared__ float4 wred[16];

  float2 z2 = make_float2(0.f, 0.f);
  float2 rsq = z2;
  if (t < NN) {
    float c = qout[b * NN + t];            // chi
    float2 rv = make_float2(-c, 1.0f);     // rhs0 = -chi ; rhs1 = ones
    r01[t] = rv; x01[t] = z2; p01[t] = z2; q01[t] = z2;
    unsigned short h0 = f2bf(rv.x), h1 = f2bf(rv.y);
    rsplit[t] = h0;            rsplit[PAD + t] = h1;
    rsplit[2 * PAD + t] = f2bf(rv.x - bf2f(h0));
    rsplit[3 * PAD + t] = f2bf(rv.y - bf2f(h1));
    rsq = make_float2(rv.x * rv.x, rv.y * rv.y);
  }
  float4 rr0 = blockReduce4(make_float4(rsq.x, rsq.y, 0.f, 0.f), wred, t);
  float tol0 = fmaxf(1e-4f * rr0.x, 1e-12f);   // rel residual 1e-2
  float tol1 = fmaxf(1e-4f * rr0.y, 1e-12f);
  bool act0 = rr0.x > tol0, act1 = rr0.y > tol1;

  const int m  = lane & 15;
  const int qd = lane >> 4;
  const unsigned short* aw0 = A + ((size_t)(2 * w) << 13) + lane * 8;
  const unsigned short* aw1 = aw0 + 8192;
  const unsigned short* bhi = rsplit + (m & 1) * PAD;
  const unsigned short* blo = rsplit + 2 * PAD + (m & 1) * PAD;

  float muold0 = 1.f, muold1 = 1.f, alold0 = 1.f, alold1 = 1.f;
  for (int k = 0; k < 24 && (act0 || act1); ++k) {
    // ---- matvec: w = A*r_hi + A*r_lo, two 16-row tiles per wave ----
    ffrag acc0 = {0.f, 0.f, 0.f, 0.f};
    ffrag acc1 = {0.f, 0.f, 0.f, 0.f};
    #pragma unroll 4
    for (int c = 0; c < 16; ++c) {
      int bo = c * 32 + qd * 8;
      bfrag bh = *reinterpret_cast<const bfrag*>(bhi + bo);
      bfrag bl = *reinterpret_cast<const bfrag*>(blo + bo);
      bfrag a0 = *reinterpret_cast<const bfrag*>(aw0 + c * 512);
      bfrag a1 = *reinterpret_cast<const bfrag*>(aw1 + c * 512);
      acc0 = __builtin_amdgcn_mfma_f32_16x16x32_bf16(a0, bh, acc0, 0, 0, 0);
      acc0 = __builtin_amdgcn_mfma_f32_16x16x32_bf16(a0, bl, acc0, 0, 0, 0);
      acc1 = __builtin_amdgcn_mfma_f32_16x16x32_bf16(a1, bh, acc1, 0, 0, 0);
      acc1 = __builtin_amdgcn_mfma_f32_16x16x32_bf16(a1, bl, acc1, 0, 0, 0);
    }
    if (m < 2) {                           // D: col=lane&15 (rhs), row=qd*4+reg
      int rbase = qd * 4;
      #pragma unroll
      for (int r = 0; r < 4; ++r) {
        reinterpret_cast<float*>(&w01[w * 32 + rbase + r])[m]      = acc0[r];
        reinterpret_cast<float*>(&w01[w * 32 + 16 + rbase + r])[m] = acc1[r];
      }
    }
    __syncthreads();

    // ---- ONE joint reduction: (r.r, r.w) for both RHS ----
    float4 dp = make_float4(0.f, 0.f, 0.f, 0.f);
    if (t < NN) {
      float2 rv = r01[t], wv = w01[t];
      dp = make_float4(rv.x * rv.x, rv.x * wv.x, rv.y * rv.y, rv.y * wv.y);
    }
    float4 s = blockReduce4(dp, wred, t);
    if (act0 && s.x <= tol0) act0 = false;
    if (act1 && s.z <= tol1) act1 = false;
    if (!act0 && !act1) break;
    float be0 = 0.f, al0 = 0.f, be1 = 0.f, al1 = 0.f;
    if (act0) {
      be0 = k ? s.x / muold0 : 0.f;
      al0 = s.x / (s.y - be0 * s.x / alold0);
      muold0 = s.x; alold0 = al0;
    }
    if (act1) {
      be1 = k ? s.z / muold1 : 0.f;
      al1 = s.z / (s.w - be1 * s.z / alold1);
      muold1 = s.z; alold1 = al1;
    }

    // ---- fused vector phase: p,q,x,r recurrences + hi/lo split of new r ----
    if (t < NN) {
      float2 rv = r01[t], wv = w01[t], pv = p01[t], qv = q01[t], xv = x01[t];
      if (act0) {
        pv.x = fmaf(be0, pv.x, rv.x);
        qv.x = fmaf(be0, qv.x, wv.x);
        xv.x = fmaf(al0, pv.x, xv.x);
        rv.x = fmaf(-al0, qv.x, rv.x);
      }
      if (act1) {
        pv.y = fmaf(be1, pv.y, rv.y);
        qv.y = fmaf(be1, qv.y, wv.y);
        xv.y = fmaf(al1, pv.y, xv.y);
        rv.y = fmaf(-al1, qv.y, rv.y);
      }
      p01[t] = pv; q01[t] = qv; x01[t] = xv; r01[t] = rv;
      unsigned short h0 = f2bf(rv.x), h1 = f2bf(rv.y);
      rsplit[t] = h0;            rsplit[PAD + t] = h1;
      rsplit[2 * PAD + t] = f2bf(rv.x - bf2f(h0));
      rsplit[3 * PAD + t] = f2bf(rv.y - bf2f(h1));
    }
    __syncthreads();
  }

  // ---- epilogue: lambda = (1'y - Q)/(1'z); charges = y - lambda*z ----
  float2 sv = z2;
  if (t < NN) sv = x01[t];
  float4 s = blockReduce4(make_float4(sv.x, sv.y, 0.f, 0.f), wred, t);
  float lam = (s.x - tq[b]) / s.y;
  if (t < NN) qout[b * NN + t] = x01[t].x - lam * x01[t].y;
}

// ---------------- fp32 fallback (round-3 structure) --------------------------
__device__ __forceinline__ float2 blockReduce2(float2 v, float2* wred, int t) {
  #pragma unroll
  for (int off = 32; off; off >>= 1) {
    v.x += __shfl_down(v.x, off, 64);
    v.y += __shfl_down(v.y, off, 64);
  }
  __syncthreads();
  if ((t & 63) == 0) wred[t >> 6] = v;
  __syncthreads();
  float2 r = wred[0];
  #pragma unroll
  for (int k = 1; k < 16; ++k) { r.x += wred[k].x; r.y += wred[k].y; }
  return r;
}

__global__ __launch_bounds__(1024) void cg_kernel_f32(
    const float* __restrict__ Aall, const float* __restrict__ tq,
    float* __restrict__ qout)
{
  int b = blockIdx.x;
  const float* A = Aall + (size_t)b * NN * NN;
  int t = threadIdx.x;
  __shared__ float2 p01[NN], q01[NN], r01[NN], x01[NN];
  __shared__ float4 sacc0[8][128];
  __shared__ float4 sacc1[8][128];
  __shared__ float2 wred[16];

  float2 z2 = make_float2(0.f, 0.f);
  float2 rsq = z2;
  if (t < NN) {
    float b0 = -qout[b * NN + t];
    x01[t] = z2;
    r01[t] = make_float2(b0, 1.0f);
    p01[t] = make_float2(b0, 1.0f);
    rsq = make_float2(b0 * b0, 1.0f);
  }
  float2 rr = blockReduce2(rsq, wred, t);
  float tol0 = fmaxf(1e-4f * rr.x, 1e-12f);
  float tol1 = fmaxf(1e-4f * rr.y, 1e-12f);
  const int c4 = (t & 127) << 2;
  const int jr = t >> 7;
  for (int it = 0; it < 24; ++it) {
    bool act0 = rr.x > tol0, act1 = rr.y > tol1;
    if (!act0 && !act1) break;
    {
      const float* ap = A + (size_t)(jr * 64) * NN + c4;
      float4 a0 = make_float4(0.f, 0.f, 0.f, 0.f);
      float4 a1 = a0;
      #pragma unroll 8
      for (int mI = 0; mI < 64; ++mI) {
        float4 av = *reinterpret_cast<const float4*>(ap);
        ap += NN;
        float2 pj = p01[jr * 64 + mI];
        a0.x = fmaf(av.x, pj.x, a0.x); a0.y = fmaf(av.y, pj.x, a0.y);
        a0.z = fmaf(av.z, pj.x, a0.z); a0.w = fmaf(av.w, pj.x, a0.w);
        a1.x = fmaf(av.x, pj.y, a1.x); a1.y = fmaf(av.y, pj.y, a1.y);
        a1.z = fmaf(av.z, pj.y, a1.z); a1.w = fmaf(av.w, pj.y, a1.w);
      }
      sacc0[jr][t & 127] = a0;
      sacc1[jr][t & 127] = a1;
    }
    __syncthreads();
    float2 dv = z2;
    if (t < NN) {
      const float* f0 = reinterpret_cast<const float*>(sacc0);
      const float* f1 = reinterpret_cast<const float*>(sacc1);
      float s0 = 0.f, s1 = 0.f;
      #pragma unroll
      for (int g = 0; g < 8; ++g) { s0 += f0[g * 512 + t]; s1 += f1[g * 512 + t]; }
      q01[t] = make_float2(s0, s1);
      float2 pv = p01[t];
      dv.x = s0 * pv.x; dv.y = s1 * pv.y;
    }
    float2 pq = blockReduce2(dv, wred, t);
    float al0 = act0 ? rr.x / pq.x : 0.f;
    float al1 = act1 ? rr.y / pq.y : 0.f;
    float2 rn = z2;
    if (t < NN) {
      float2 xv = x01[t], rv = r01[t], pv = p01[t], qv = q01[t];
      xv.x = fmaf(al0, pv.x, xv.x);  xv.y = fmaf(al1, pv.y, xv.y);
      rv.x = fmaf(-al0, qv.x, rv.x); rv.y = fmaf(-al1, qv.y, rv.y);
      x01[t] = xv; r01[t] = rv;
      rn.x = rv.x * rv.x; rn.y = rv.y * rv.y;
    }
    float2 rrn = blockReduce2(rn, wred, t);
    float be0 = act0 ? rrn.x / rr.x : 0.f;
    float be1 = act1 ? rrn.y / rr.y : 0.f;
    if (t < NN) {
      float2 rv = r01[t], pv = p01[t];
      pv.x = fmaf(be0, pv.x, rv.x);
      pv.y = fmaf(be1, pv.y, rv.y);
      p01[t] = pv;
    }
    rr = rrn;
    __syncthreads();
  }
  float2 sv = z2;
  if (t < NN) sv = x01[t];
  float2 s = blockReduce2(sv, wred, t);
  float lam = (s.x - tq[b]) / s.y;
  if (t < NN) qout[b * NN + t] = x01[t].x - lam * x01[t].y;
}

extern "C" void kernel_launch(void* const* d_in, const int* in_sizes, int n_in,
                              void* d_out, int out_size, void* d_ws, size_t ws_size,
                              hipStream_t stream) {
  const float* pos      = (const float*)d_in[0];
  const float* feats    = (const float*)d_in[1];
  const int*   ntype    = (const int*)  d_in[2];
  const float* tq       = (const float*)d_in[3];
  const float* hardness = (const float*)d_in[4];
  const float* sigma    = (const float*)d_in[5];
  const float* W1 = (const float*)d_in[6];
  const float* b1 = (const float*)d_in[7];
  const float* W2 = (const float*)d_in[8];
  const float* b2 = (const float*)d_in[9];
  const float* W3 = (const float*)d_in[10];
  const float* b3 = (const float*)d_in[11];

  float* out  = (float*)d_out;
  float* chi  = out;             // charges region doubles as chi scratch
  float* Aout = out + BB * NN;   // output 1: A, batch-major

  const size_t bf_bytes = (size_t)BB * NN * NN * sizeof(unsigned short);
  const bool use_bf = ws_size >= bf_bytes;
  unsigned short* Abf = use_bf ? (unsigned short*)d_ws : nullptr;

  chi_kernel<<<dim3(BB * NN / 16), dim3(256), 0, stream>>>(feats, W1, b1, W2, b2, W3, b3, chi);
  build_A_kernel<<<dim3(NN / 16, BB), dim3(256), 0, stream>>>(pos, ntype, hardness, sigma, Aout, Abf);
  if (use_bf)
    cg_kernel_bf<<<dim3(BB), dim3(1024), 0, stream>>>(Abf, tq, chi);
  else
    cg_kernel_f32<<<dim3(BB), dim3(1024), 0, stream>>>(Aout, tq, chi);
}

// Round 10
// 249.060 us; speedup vs baseline: 1.3311x; 1.0238x over previous
//
#include <hip/hip_runtime.h>
#include <math.h>

constexpr int BB = 64, NN = 512, DD = 128, UU = 64;
constexpr float KCOUL = 14.399645351950548f;
constexpr float NOISEF = 1e-8f;
#define M_PIF 3.14159265358979323846f

typedef __attribute__((ext_vector_type(8))) short bfrag;   // 8 bf16 (4 VGPRs)
typedef __attribute__((ext_vector_type(4))) float ffrag;   // 4 fp32 acc

__device__ __forceinline__ unsigned short f2bf(float f) {   // RNE float->bf16
  unsigned int u = __float_as_uint(f);
  u += 0x7fffu + ((u >> 16) & 1u);
  return (unsigned short)(u >> 16);
}
__device__ __forceinline__ float bf2f(unsigned short h) {
  return __uint_as_float((unsigned int)h << 16);
}
// Two-regime erf (rel-accurate near 0 — required inside erf(x)/x):
__device__ __forceinline__ float fast_erf(float x) {
  float t2 = x * x;
  float small_v = 1.1283791671f * x *
      fmaf(t2, fmaf(t2, fmaf(t2, fmaf(t2, 4.6296296e-3f, -2.3809524e-2f),
                             0.1f), -0.33333333f), 1.0f);
  float t = __builtin_amdgcn_rcpf(fmaf(0.3275911f, x, 1.0f));
  float p = fmaf(fmaf(fmaf(fmaf(1.061405429f, t, -1.453152027f),
                           t, 1.421413741f), t, -0.284496736f), t, 0.254829592f);
  float big_v = fmaf(-p * t, __expf(-t2), 1.0f);
  return x < 0.5f ? small_v : big_v;
}
__device__ __forceinline__ float fast_tanh(float x) {      // rel err ~1e-6
  float ax = fabsf(x);
  float e = __expf(2.0f * ax);
  float t = 1.0f - 2.0f * __builtin_amdgcn_rcpf(e + 1.0f);
  return __builtin_copysignf(t, x);
}

// ------- chi MLP: 4 rows per wave, scalar(SGPR) feats, W1/W2 amortized -------
__global__ __launch_bounds__(256) void chi_kernel(
    const float* __restrict__ feats, const float* __restrict__ W1,
    const float* __restrict__ b1, const float* __restrict__ W2,
    const float* __restrict__ b2, const float* __restrict__ W3,
    const float* __restrict__ b3, float* __restrict__ chi)
{
  int wave = threadIdx.x >> 6, lane = threadIdx.x & 63;
  int row0 = __builtin_amdgcn_readfirstlane((blockIdx.x * 4 + wave) * 4);
  const float* f = feats + (size_t)row0 * DD;   // SGPR base -> s_load
  __shared__ float sh[4][4][UU];

  float a0 = b1[lane], a1 = a0, a2 = a0, a3 = a0;
  #pragma unroll 8
  for (int d = 0; d < DD; ++d) {
    float wv = W1[d * UU + lane];               // coalesced, L1-resident
    a0 = fmaf(f[d],          wv, a0);
    a1 = fmaf(f[DD + d],     wv, a1);
    a2 = fmaf(f[2 * DD + d], wv, a2);
    a3 = fmaf(f[3 * DD + d], wv, a3);
  }
  sh[wave][0][lane] = a0 - fast_tanh(a0);
  sh[wave][1][lane] = a1 - fast_tanh(a1);
  sh[wave][2][lane] = a2 - fast_tanh(a2);
  sh[wave][3][lane] = a3 - fast_tanh(a3);
  __builtin_amdgcn_s_waitcnt(0);                // lgkm drain before ds_read
  float c0 = b2[lane], c1 = c0, c2 = c0, c3 = c0;
  #pragma unroll 8
  for (int u = 0; u < UU; ++u) {
    float wv = W2[u * UU + lane];
    c0 = fmaf(sh[wave][0][u], wv, c0);          // LDS same-addr broadcast
    c1 = fmaf(sh[wave][1][u], wv, c1);
    c2 = fmaf(sh[wave][2][u], wv, c2);
    c3 = fmaf(sh[wave][3][u], wv, c3);
  }
  float w3 = W3[lane];
  float p0 = (c0 - fast_tanh(c0)) * w3;
  float p1 = (c1 - fast_tanh(c1)) * w3;
  float p2 = (c2 - fast_tanh(c2)) * w3;
  float p3 = (c3 - fast_tanh(c3)) * w3;
  #pragma unroll
  for (int off = 32; off; off >>= 1) {
    p0 += __shfl_down(p0, off, 64);
    p1 += __shfl_down(p1, off, 64);
    p2 += __shfl_down(p2, off, 64);
    p3 += __shfl_down(p3, off, 64);
  }
  if (lane == 0) {
    float bb = b3[0];
    float z0 = p0 + bb, z1 = p1 + bb, z2v = p2 + bb, z3 = p3 + bb;
    chi[row0]     = z0 - fast_tanh(z0);
    chi[row0 + 1] = z1 - fast_tanh(z1);
    chi[row0 + 2] = z2v - fast_tanh(z2v);
    chi[row0 + 3] = z3 - fast_tanh(z3);
  }
}

// ------ build A (fp32 coalesced to d_out) + bf16 frag-tile staged in LDS -----
// frag layout: (i,j) -> (i>>4)*8192 + (j>>5)*512 + ((j>>3)&3)*128 + (i&15)*8 + (j&7)
__global__ __launch_bounds__(256) void build_A_kernel(
    const float* __restrict__ pos, const int* __restrict__ ntype,
    const float* __restrict__ hardness, const float* __restrict__ sigma,
    float* __restrict__ Aout, unsigned short* __restrict__ Abf)
{
  int b = blockIdx.y;
  int r0 = blockIdx.x * 16;                  // exactly one 16-row frag tile
  __shared__ float px[NN], py[NN], pz[NN], s2[NN], hd[NN];
  __shared__ unsigned short tile[16 * NN];   // 16 KB frag-major bf16
  for (int n = threadIdx.x; n < NN; n += 256) {
    const float* p = pos + ((size_t)b * NN + n) * 3;
    px[n] = p[0]; py[n] = p[1]; pz[n] = p[2];
    int ty = ntype[b * NN + n];
    float s = sigma[ty];
    s2[n] = s * s;
    hd[n] = hardness[ty];
  }
  __syncthreads();
  int c0 = (threadIdx.x & 127) << 2;
  int rsub = threadIdx.x >> 7;
  float* outB = Aout + (size_t)b * NN * NN;
  for (int k = 0; k < 8; ++k) {
    int i = r0 + (k << 1) + rsub;
    float pxi = px[i], pyi = py[i], pzi = pz[i], s2i = s2[i];
    float4 v;
    float* vp = &v.x;
    #pragma unroll
    for (int c = 0; c < 4; ++c) {
      int j = c0 + c;
      float dx = pxi - px[j], dy = pyi - py[j], dz = pzi - pz[j];
      float d = sqrtf(fmaf(dx, dx, fmaf(dy, dy, dz * dz))) + NOISEF;
      float arg = d * __builtin_amdgcn_rsqf(2.0f * (s2i + s2[j]));
      float val = KCOUL * fast_erf(arg) * __builtin_amdgcn_rcpf(d);
      if (j == i) val += hd[i] + KCOUL * __builtin_amdgcn_rsqf(2.0f * M_PIF * s2i);
      vp[c] = val;
    }
    *reinterpret_cast<float4*>(outB + (size_t)i * NN + c0) = v;
    if (Abf) {
      ushort4 wv;
      wv.x = f2bf(v.x); wv.y = f2bf(v.y); wv.z = f2bf(v.z); wv.w = f2bf(v.w);
      int loc = ((c0 >> 5) << 9) + (((c0 >> 3) & 3) << 7) + ((i & 15) << 3) + (c0 & 7);
      *reinterpret_cast<ushort4*>(tile + loc) = wv;
    }
  }
  if (Abf) {
    __syncthreads();
    const uint4* src = reinterpret_cast<const uint4*>(tile);
    uint4* dst = reinterpret_cast<uint4*>(Abf + (size_t)b * NN * NN +
                                          ((size_t)(r0 >> 4) << 13));
    #pragma unroll
    for (int k = 0; k < 4; ++k)                 // 1024 uint4 = 16 KB coalesced
      dst[threadIdx.x + k * 256] = src[threadIdx.x + k * 256];
  }
}

// ------- Chronopoulos-Gear CG, register-state, 2 barriers/iter ---------------
// wave w owns rows [32w,32w+32): lane holds (row=w*32+(lane>>1), rhs=lane&1)
// for p,q,x,r.  Shared state: rsplit (bf16 hi/lo of r, for B-frags) + per-wave
// w01 strip (same-wave LDS round trip, no barrier) + wred (16 float4).
__global__ __launch_bounds__(1024) void cg_kernel_bf(
    const unsigned short* __restrict__ Abf, const float* __restrict__ tq,
    float* __restrict__ qout /* in: chi, out: charges */)
{
  int b = blockIdx.x;
  const unsigned short* A = Abf + (size_t)b * NN * NN;
  int t = threadIdx.x;
  int lane = t & 63, w = t >> 6;          // 16 waves
  constexpr int PAD = NN + 32;            // hi0/hi1 16 banks apart
  __shared__ __align__(16) unsigned short rsplit[4 * PAD]; // hi0,hi1,lo0,lo1
  __shared__ float w01[2 * NN];           // [row*2 + rhs]
  __shared__ float4 wred[16];

  const int row = w * 32 + (lane >> 1);
  const int rhs = lane & 1;
  const int m  = lane & 15;               // A row-in-tile / D col (=rhs)
  const int qd = lane >> 4;               // quad: k-subrange qd*8..+7
  const unsigned short* aw0 = A + ((size_t)(2 * w) << 13) + lane * 8;
  const unsigned short* aw1 = aw0 + 8192;
  const unsigned short* bhi = rsplit + (m & 1) * PAD;
  const unsigned short* blo = rsplit + 2 * PAD + (m & 1) * PAD;

  // ---- init: r = rhs (rhs0 = -chi, rhs1 = ones); x=p=q=0 ----
  float rv = rhs ? 1.0f : -qout[b * NN + row];
  float xv = 0.f, pv = 0.f, qv = 0.f;
  {
    unsigned short h = f2bf(rv);
    rsplit[rhs * PAD + row] = h;
    rsplit[2 * PAD + rhs * PAD + row] = f2bf(rv - bf2f(h));
  }
  float rr = rv * rv;                      // parity-preserving reduce
  #pragma unroll
  for (int off = 2; off < 64; off <<= 1) rr += __shfl_down(rr, off, 64);
  if (lane < 2) reinterpret_cast<float2*>(&wred[w])[lane] = make_float2(rr, 0.f);
  __syncthreads();
  float mu0 = 0.f, mu1 = 0.f;
  #pragma unroll
  for (int g = 0; g < 16; ++g) { mu0 += wred[g].x; mu1 += wred[g].z; }
  float tol0 = fmaxf(1e-4f * mu0, 1e-12f);   // rel residual 1e-2
  float tol1 = fmaxf(1e-4f * mu1, 1e-12f);
  bool act0 = mu0 > tol0, act1 = mu1 > tol1;
  __syncthreads();                         // protect wred before iter-0 rewrite

  float muold0 = 1.f, muold1 = 1.f, alold0 = 1.f, alold1 = 1.f;
  for (int k = 0; k < 24 && (act0 || act1); ++k) {
    // ---- matvec: w = A*r_hi + A*r_lo, two 16-row tiles per wave ----
    ffrag acc0 = {0.f, 0.f, 0.f, 0.f};
    ffrag acc1 = {0.f, 0.f, 0.f, 0.f};
    #pragma unroll 4
    for (int c = 0; c < 16; ++c) {
      int bo = c * 32 + qd * 8;
      bfrag bh = *reinterpret_cast<const bfrag*>(bhi + bo);
      bfrag bl = *reinterpret_cast<const bfrag*>(blo + bo);
      bfrag a0 = *reinterpret_cast<const bfrag*>(aw0 + c * 512);
      bfrag a1 = *reinterpret_cast<const bfrag*>(aw1 + c * 512);
      acc0 = __builtin_amdgcn_mfma_f32_16x16x32_bf16(a0, bh, acc0, 0, 0, 0);
      acc0 = __builtin_amdgcn_mfma_f32_16x16x32_bf16(a0, bl, acc0, 0, 0, 0);
      acc1 = __builtin_amdgcn_mfma_f32_16x16x32_bf16(a1, bh, acc1, 0, 0, 0);
      acc1 = __builtin_amdgcn_mfma_f32_16x16x32_bf16(a1, bl, acc1, 0, 0, 0);
    }
    // D: col=lane&15 (rhs), row-in-tile = qd*4+reg.  Own-strip write:
    if (m < 2) {
      int rbase = qd * 4;
      #pragma unroll
      for (int r = 0; r < 4; ++r) {
        w01[(w * 32 + rbase + r) * 2 + m]      = acc0[r];
        w01[(w * 32 + 16 + rbase + r) * 2 + m] = acc1[r];
      }
    }
    float wv = w01[row * 2 + rhs];         // same-wave LDS round trip (no barrier)

    // ---- per-wave dot partials (mu=r.r, nu=r.w), parity-preserving ----
    float pr = rv * rv, pw = rv * wv;
    #pragma unroll
    for (int off = 2; off < 64; off <<= 1) {
      pr += __shfl_down(pr, off, 64);
      pw += __shfl_down(pw, off, 64);
    }
    if (lane < 2) reinterpret_cast<float2*>(&wred[w])[lane] = make_float2(pr, pw);
    __syncthreads();                       // BARRIER A

    float s0 = 0.f, n0 = 0.f, s1 = 0.f, n1 = 0.f;
    #pragma unroll
    for (int g = 0; g < 16; ++g) {
      float4 u = wred[g];
      s0 += u.x; n0 += u.y; s1 += u.z; n1 += u.w;
    }
    if (act0 && s0 <= tol0) act0 = false;
    if (act1 && s1 <= tol1) act1 = false;
    if (!act0 && !act1) break;             // uniform decision
    float be0 = 0.f, al0 = 0.f, be1 = 0.f, al1 = 0.f;
    if (act0) {
      be0 = k ? s0 / muold0 : 0.f;
      al0 = s0 / (n0 - be0 * s0 / alold0);
      muold0 = s0; alold0 = al0;
    }
    if (act1) {
      be1 = k ? s1 / muold1 : 0.f;
      al1 = s1 / (n1 - be1 * s1 / alold1);
      muold1 = s1; alold1 = al1;
    }
    float be = rhs ? be1 : be0;
    float al = rhs ? al1 : al0;

    // ---- register vector phase + bf16 hi/lo split of new r ----
    pv = fmaf(be, pv, rv);
    qv = fmaf(be, qv, wv);
    xv = fmaf(al, pv, xv);
    rv = fmaf(-al, qv, rv);
    unsigned short h = f2bf(rv);
    rsplit[rhs * PAD + row] = h;
    rsplit[2 * PAD + rhs * PAD + row] = f2bf(rv - bf2f(h));
    __syncthreads();                       // BARRIER B
  }

  // ---- epilogue: lambda = (1'y - Q)/(1'z); charges = y - lambda*z ----
  __syncthreads();                         // all done reading wred
  float sx = xv;
  #pragma unroll
  for (int off = 2; off < 64; off <<= 1) sx += __shfl_down(sx, off, 64);
  if (lane < 2) reinterpret_cast<float2*>(&wred[w])[lane] = make_float2(sx, 0.f);
  __syncthreads();
  float sum0 = 0.f, sum1 = 0.f;
  #pragma unroll
  for (int g = 0; g < 16; ++g) { sum0 += wred[g].x; sum1 += wred[g].z; }
  float lam = (sum0 - tq[b]) / sum1;
  float xpart = __shfl_xor(xv, 1, 64);     // partner's x (other rhs)
  if (rhs == 0) qout[b * NN + row] = xv - lam * xpart;
}

// ---------------- fp32 fallback (round-3 structure) --------------------------
__device__ __forceinline__ float2 blockReduce2(float2 v, float2* wred, int t) {
  #pragma unroll
  for (int off = 32; off; off >>= 1) {
    v.x += __shfl_down(v.x, off, 64);
    v.y += __shfl_down(v.y, off, 64);
  }
  __syncthreads();
  if ((t & 63) == 0) wred[t >> 6] = v;
  __syncthreads();
  float2 r = wred[0];
  #pragma unroll
  for (int k = 1; k < 16; ++k) { r.x += wred[k].x; r.y += wred[k].y; }
  return r;
}

__global__ __launch_bounds__(1024) void cg_kernel_f32(
    const float* __restrict__ Aall, const float* __restrict__ tq,
    float* __restrict__ qout)
{
  int b = blockIdx.x;
  const float* A = Aall + (size_t)b * NN * NN;
  int t = threadIdx.x;
  __shared__ float2 p01[NN], q01[NN], r01[NN], x01[NN];
  __shared__ float4 sacc0[8][128];
  __shared__ float4 sacc1[8][128];
  __shared__ float2 wred[16];

  float2 z2 = make_float2(0.f, 0.f);
  float2 rsq = z2;
  if (t < NN) {
    float b0 = -qout[b * NN + t];
    x01[t] = z2;
    r01[t] = make_float2(b0, 1.0f);
    p01[t] = make_float2(b0, 1.0f);
    rsq = make_float2(b0 * b0, 1.0f);
  }
  float2 rr = blockReduce2(rsq, wred, t);
  float tol0 = fmaxf(1e-4f * rr.x, 1e-12f);
  float tol1 = fmaxf(1e-4f * rr.y, 1e-12f);
  const int c4 = (t & 127) << 2;
  const int jr = t >> 7;
  for (int it = 0; it < 24; ++it) {
    bool act0 = rr.x > tol0, act1 = rr.y > tol1;
    if (!act0 && !act1) break;
    {
      const float* ap = A + (size_t)(jr * 64) * NN + c4;
      float4 a0 = make_float4(0.f, 0.f, 0.f, 0.f);
      float4 a1 = a0;
      #pragma unroll 8
      for (int mI = 0; mI < 64; ++mI) {
        float4 av = *reinterpret_cast<const float4*>(ap);
        ap += NN;
        float2 pj = p01[jr * 64 + mI];
        a0.x = fmaf(av.x, pj.x, a0.x); a0.y = fmaf(av.y, pj.x, a0.y);
        a0.z = fmaf(av.z, pj.x, a0.z); a0.w = fmaf(av.w, pj.x, a0.w);
        a1.x = fmaf(av.x, pj.y, a1.x); a1.y = fmaf(av.y, pj.y, a1.y);
        a1.z = fmaf(av.z, pj.y, a1.z); a1.w = fmaf(av.w, pj.y, a1.w);
      }
      sacc0[jr][t & 127] = a0;
      sacc1[jr][t & 127] = a1;
    }
    __syncthreads();
    float2 dv = z2;
    if (t < NN) {
      const float* f0 = reinterpret_cast<const float*>(sacc0);
      const float* f1 = reinterpret_cast<const float*>(sacc1);
      float s0 = 0.f, s1 = 0.f;
      #pragma unroll
      for (int g = 0; g < 8; ++g) { s0 += f0[g * 512 + t]; s1 += f1[g * 512 + t]; }
      q01[t] = make_float2(s0, s1);
      float2 pv = p01[t];
      dv.x = s0 * pv.x; dv.y = s1 * pv.y;
    }
    float2 pq = blockReduce2(dv, wred, t);
    float al0 = act0 ? rr.x / pq.x : 0.f;
    float al1 = act1 ? rr.y / pq.y : 0.f;
    float2 rn = z2;
    if (t < NN) {
      float2 xv = x01[t], rv = r01[t], pv = p01[t], qv = q01[t];
      xv.x = fmaf(al0, pv.x, xv.x);  xv.y = fmaf(al1, pv.y, xv.y);
      rv.x = fmaf(-al0, qv.x, rv.x); rv.y = fmaf(-al1, qv.y, rv.y);
      x01[t] = xv; r01[t] = rv;
      rn.x = rv.x * rv.x; rn.y = rv.y * rv.y;
    }
    float2 rrn = blockReduce2(rn, wred, t);
    float be0 = act0 ? rrn.x / rr.x : 0.f;
    float be1 = act1 ? rrn.y / rr.y : 0.f;
    if (t < NN) {
      float2 rv = r01[t], pv = p01[t];
      pv.x = fmaf(be0, pv.x, rv.x);
      pv.y = fmaf(be1, pv.y, rv.y);
      p01[t] = pv;
    }
    rr = rrn;
    __syncthreads();
  }
  float2 sv = z2;
  if (t < NN) sv = x01[t];
  float2 s = blockReduce2(sv, wred, t);
  float lam = (s.x - tq[b]) / s.y;
  if (t < NN) qout[b * NN + t] = x01[t].x - lam * x01[t].y;
}

extern "C" void kernel_launch(void* const* d_in, const int* in_sizes, int n_in,
                              void* d_out, int out_size, void* d_ws, size_t ws_size,
                              hipStream_t stream) {
  const float* pos      = (const float*)d_in[0];
  const float* feats    = (const float*)d_in[1];
  const int*   ntype    = (const int*)  d_in[2];
  const float* tq       = (const float*)d_in[3];
  const float* hardness = (const float*)d_in[4];
  const float* sigma    = (const float*)d_in[5];
  const float* W1 = (const float*)d_in[6];
  const float* b1 = (const float*)d_in[7];
  const float* W2 = (const float*)d_in[8];
  const float* b2 = (const float*)d_in[9];
  const float* W3 = (const float*)d_in[10];
  const float* b3 = (const float*)d_in[11];

  float* out  = (float*)d_out;
  float* chi  = out;             // charges region doubles as chi scratch
  float* Aout = out + BB * NN;   // output 1: A, batch-major

  const size_t bf_bytes = (size_t)BB * NN * NN * sizeof(unsigned short);
  const bool use_bf = ws_size >= bf_bytes;
  unsigned short* Abf = use_bf ? (unsigned short*)d_ws : nullptr;

  chi_kernel<<<dim3(BB * NN / 16), dim3(256), 0, stream>>>(feats, W1, b1, W2, b2, W3, b3, chi);
  build_A_kernel<<<dim3(NN / 16, BB), dim3(256), 0, stream>>>(pos, ntype, hardness, sigma, Aout, Abf);
  if (use_bf)
    cg_kernel_bf<<<dim3(BB), dim3(1024), 0, stream>>>(Abf, tq, chi);
  else
    cg_kernel_f32<<<dim3(BB), dim3(1024), 0, stream>>>(Aout, tq, chi);
}